// Round 4
// baseline (16251.176 us; speedup 1.0000x reference)
//
#include <hip/hip_runtime.h>
#include <hip/hip_bf16.h>
#include <math.h>

// WaveNet forward, fp32. B=8, T=16384, R=128, G=256, S=128, K=3, 20 blocks.
#define TA    16384
#define NBLK  20
#define RCH   128
#define GCH   256
#define MELSC 80
#define BB    8
#define MROWS (BB * TA)          // 131072 rows of [channels]
#define SQRT_HALF 0.70710678118654752440f

// ---------------------------------------------------------------- upsample ---
// transposed conv1d per (b,mel) row: out[p][t] = sum_j w[j] * in[p][(t+j-pad_a)/s]
__global__ void upsample_k(const float* __restrict__ in, float* __restrict__ out,
                           const float* __restrict__ w,
                           int Tin, int Tout, int s, int k, int pad_a,
                           int P, int transposed)
{
    int idx = blockIdx.x * blockDim.x + threadIdx.x;
    if (idx >= P * Tout) return;
    int p = idx / Tout;
    int t = idx - p * Tout;
    float acc = 0.f;
    for (int j = 0; j < k; ++j) {
        int q = t + j - pad_a;
        if (q >= 0 && (q % s) == 0) {
            int i = q / s;
            if (i < Tin) acc += w[j] * in[p * Tin + i];
        }
    }
    if (!transposed) {
        out[p * Tout + t] = acc;
    } else {            // write cond as [B, T, MELS]
        int b = p / MELSC;
        int m = p - b * MELSC;
        out[((size_t)b * Tout + t) * MELSC + m] = acc;
    }
}

// ------------------------------------------------------------- first conv ---
// x = inputs @ first_w + first_b  (K=256 -> N=128); also zero-init skips.
__launch_bounds__(256, 2)
__global__ void first_k(const float* __restrict__ inp,   // [M,256]
                        const float* __restrict__ W,     // [256][128]
                        const float* __restrict__ bias,  // [128]
                        float* __restrict__ x,           // [M,128]
                        float* __restrict__ skips)       // [M,128]
{
    __shared__ __align__(16) float A[16][68];
    __shared__ __align__(16) float Bm[16 * 128];
    const int tid  = threadIdx.x;
    const int tn   = tid & 15;        // col group: cols tn*8 .. +7
    const int tm   = tid >> 4;        // row group: rows tm*4 .. +3
    const int arow = tid >> 2;        // staging: row 0..63
    const int ak4  = (tid & 3) * 4;   // staging: k offset
    const int r0   = blockIdx.x * 64;

    float acc[4][8];
#pragma unroll
    for (int r = 0; r < 4; ++r)
#pragma unroll
        for (int j = 0; j < 8; ++j) acc[r][j] = 0.f;

    float4 av, bv0, bv1;
    auto loadch = [&](int ch) {
        av  = *(const float4*)(inp + (size_t)(r0 + arow) * 256 + ch * 16 + ak4);
        bv0 = *(const float4*)(W + ch * 2048 + tid * 4);
        bv1 = *(const float4*)(W + ch * 2048 + 1024 + tid * 4);
    };
    loadch(0);
    for (int ch = 0; ch < 16; ++ch) {
        __syncthreads();
        A[ak4 + 0][arow] = av.x; A[ak4 + 1][arow] = av.y;
        A[ak4 + 2][arow] = av.z; A[ak4 + 3][arow] = av.w;
        *(float4*)(Bm + tid * 4) = bv0;
        *(float4*)(Bm + 1024 + tid * 4) = bv1;
        __syncthreads();
        if (ch < 15) loadch(ch + 1);
#pragma unroll
        for (int k = 0; k < 16; ++k) {
            const float4 a4 = *(const float4*)&A[k][tm * 4];
            const float4 b0 = *(const float4*)&Bm[k * 128 + tn * 8];
            const float4 b1 = *(const float4*)&Bm[k * 128 + tn * 8 + 4];
            const float aa[4]  = {a4.x, a4.y, a4.z, a4.w};
            const float bb8[8] = {b0.x, b0.y, b0.z, b0.w, b1.x, b1.y, b1.z, b1.w};
#pragma unroll
            for (int r = 0; r < 4; ++r)
#pragma unroll
                for (int j = 0; j < 8; ++j) acc[r][j] += aa[r] * bb8[j];
        }
    }
    const int c0 = tn * 8;
    const float4 bi0 = *(const float4*)(bias + c0);
    const float4 bi1 = *(const float4*)(bias + c0 + 4);
#pragma unroll
    for (int r = 0; r < 4; ++r) {
        const int row = r0 + tm * 4 + r;
        float4 o0 = {acc[r][0] + bi0.x, acc[r][1] + bi0.y, acc[r][2] + bi0.z, acc[r][3] + bi0.w};
        float4 o1 = {acc[r][4] + bi1.x, acc[r][5] + bi1.y, acc[r][6] + bi1.z, acc[r][7] + bi1.w};
        *(float4*)(x + (size_t)row * 128 + c0)     = o0;
        *(float4*)(x + (size_t)row * 128 + c0 + 4) = o1;
        float4 z4 = {0.f, 0.f, 0.f, 0.f};
        *(float4*)(skips + (size_t)row * 128 + c0)     = z4;
        *(float4*)(skips + (size_t)row * 128 + c0 + 4) = z4;
    }
}

// ---------------------------------------------------------- residual block ---
// g = dconv(x) + bd + cond@Wc ; z = tanh(a)*sigmoid(b)
// skips += z@Ws + bs ; xn = (x + z@Wo + bo) * sqrt(0.5)
__launch_bounds__(256, 2)
__global__ void block_k(const float* __restrict__ x, float* __restrict__ xn,
                        const float* __restrict__ cond,
                        float* __restrict__ skips,
                        const float* __restrict__ Wd, const float* __restrict__ bd,
                        const float* __restrict__ Wc,
                        const float* __restrict__ Ws, const float* __restrict__ bs,
                        const float* __restrict__ Wo, const float* __restrict__ bo,
                        int d)
{
    __shared__ __align__(16) float A[16][68];
    __shared__ __align__(16) float Bm[16 * 256];
    __shared__ __align__(16) float zt[128][68];

    const int tid  = threadIdx.x;
    const int tn   = tid & 15;
    const int tm   = tid >> 4;
    const int arow = tid >> 2;
    const int ak4  = (tid & 3) * 4;
    const int r0   = blockIdx.x * 64;
    const int b    = r0 / TA;
    const int t0   = r0 - b * TA;
    const float* xb = x + (size_t)b * TA * RCH;

    float acc[4][16];
#pragma unroll
    for (int r = 0; r < 4; ++r)
#pragma unroll
        for (int j = 0; j < 16; ++j) acc[r][j] = 0.f;

    // ---- stage 1: g[64 x 256] over K = 3*128 (taps) + 80 (cond) = 29 chunks
    float4 av, bv[4];
    auto loadch = [&](int ch) {
        if (ch < 24) {
            const int tap = ch >> 3;
            const int kc  = (ch & 7) * 16;
            const int ts  = t0 + arow - (2 - tap) * d;
            if (ts >= 0) av = *(const float4*)(xb + (size_t)ts * RCH + kc + ak4);
            else         av = make_float4(0.f, 0.f, 0.f, 0.f);
            const float* bsrc = Wd + ch * (16 * 256);
#pragma unroll
            for (int j = 0; j < 4; ++j)
                bv[j] = *(const float4*)(bsrc + j * 1024 + tid * 4);
        } else {
            const int kc = (ch - 24) * 16;
            av = *(const float4*)(cond + ((size_t)b * TA + (t0 + arow)) * MELSC + kc + ak4);
            const float* bsrc = Wc + (ch - 24) * (16 * 256);
#pragma unroll
            for (int j = 0; j < 4; ++j)
                bv[j] = *(const float4*)(bsrc + j * 1024 + tid * 4);
        }
    };
    loadch(0);
    for (int ch = 0; ch < 29; ++ch) {
        __syncthreads();
        A[ak4 + 0][arow] = av.x; A[ak4 + 1][arow] = av.y;
        A[ak4 + 2][arow] = av.z; A[ak4 + 3][arow] = av.w;
#pragma unroll
        for (int j = 0; j < 4; ++j)
            *(float4*)(Bm + j * 1024 + tid * 4) = bv[j];
        __syncthreads();
        if (ch < 28) loadch(ch + 1);
#pragma unroll
        for (int k = 0; k < 16; ++k) {
            const float4 a4 = *(const float4*)&A[k][tm * 4];
            const float4 b0 = *(const float4*)&Bm[k * 256 + tn * 8];
            const float4 b1 = *(const float4*)&Bm[k * 256 + tn * 8 + 4];
            const float4 b2 = *(const float4*)&Bm[k * 256 + tn * 8 + 128];
            const float4 b3 = *(const float4*)&Bm[k * 256 + tn * 8 + 132];
            const float aa[4]   = {a4.x, a4.y, a4.z, a4.w};
            const float bb16[16] = {b0.x, b0.y, b0.z, b0.w, b1.x, b1.y, b1.z, b1.w,
                                    b2.x, b2.y, b2.z, b2.w, b3.x, b3.y, b3.z, b3.w};
#pragma unroll
            for (int r = 0; r < 4; ++r)
#pragma unroll
                for (int j = 0; j < 16; ++j) acc[r][j] += aa[r] * bb16[j];
        }
    }

    // ---- GLU (thread-local: cols c0..c0+7 pair with 128+c0..): z -> zt (transposed)
    const int c0 = tn * 8;
#pragma unroll
    for (int r = 0; r < 4; ++r)
#pragma unroll
        for (int j = 0; j < 8; ++j) {
            const float a = acc[r][j]     + bd[c0 + j];
            const float g = acc[r][8 + j] + bd[128 + c0 + j];
            const float z = tanhf(a) * (1.f / (1.f + expf(-g)));
            zt[c0 + j][tm * 4 + r] = z;
        }

    // ---- stage 2: [skip | xo] = z @ [Ws | Wo], K=128, N=256 (8 chunks)
    float acc2[4][16];
#pragma unroll
    for (int r = 0; r < 4; ++r)
#pragma unroll
        for (int j = 0; j < 16; ++j) acc2[r][j] = 0.f;

    const int half = tid >> 7;            // 0 -> Ws (cols 0..127), 1 -> Wo (128..255)
    const int st   = tid & 127;
    const float* W2 = half ? Wo : Ws;
    float4 b2v[4];
    auto loadch2 = [&](int ch) {
#pragma unroll
        for (int j = 0; j < 4; ++j) {
            const int f  = j * 512 + st * 4;   // flat in [16][128]
            const int kk = f >> 7;
            const int cc = f & 127;
            b2v[j] = *(const float4*)(W2 + (ch * 16 + kk) * 128 + cc);
        }
    };
    loadch2(0);
    for (int ch = 0; ch < 8; ++ch) {
        __syncthreads();                   // also publishes zt on ch==0
#pragma unroll
        for (int j = 0; j < 4; ++j) {
            const int f  = j * 512 + st * 4;
            const int kk = f >> 7;
            const int cc = f & 127;
            *(float4*)(Bm + kk * 256 + half * 128 + cc) = b2v[j];
        }
        __syncthreads();
        if (ch < 7) loadch2(ch + 1);
#pragma unroll
        for (int k = 0; k < 16; ++k) {
            const float4 a4 = *(const float4*)&zt[ch * 16 + k][tm * 4];
            const float4 b0 = *(const float4*)&Bm[k * 256 + tn * 8];
            const float4 b1 = *(const float4*)&Bm[k * 256 + tn * 8 + 4];
            const float4 b2 = *(const float4*)&Bm[k * 256 + tn * 8 + 128];
            const float4 b3 = *(const float4*)&Bm[k * 256 + tn * 8 + 132];
            const float aa[4]   = {a4.x, a4.y, a4.z, a4.w};
            const float bb16[16] = {b0.x, b0.y, b0.z, b0.w, b1.x, b1.y, b1.z, b1.w,
                                    b2.x, b2.y, b2.z, b2.w, b3.x, b3.y, b3.z, b3.w};
#pragma unroll
            for (int r = 0; r < 4; ++r)
#pragma unroll
                for (int j = 0; j < 16; ++j) acc2[r][j] += aa[r] * bb16[j];
        }
    }

    // ---- epilogue: skips += skip+bs ; xn = (x + xo + bo) * sqrt(0.5)
    const float4 bs0 = *(const float4*)(bs + c0);
    const float4 bs1 = *(const float4*)(bs + c0 + 4);
    const float4 bo0 = *(const float4*)(bo + c0);
    const float4 bo1 = *(const float4*)(bo + c0 + 4);
#pragma unroll
    for (int r = 0; r < 4; ++r) {
        const int row = r0 + tm * 4 + r;
        float* sp = skips + (size_t)row * 128 + c0;
        float4 s0 = *(float4*)sp;
        float4 s1 = *(float4*)(sp + 4);
        s0.x += acc2[r][0] + bs0.x; s0.y += acc2[r][1] + bs0.y;
        s0.z += acc2[r][2] + bs0.z; s0.w += acc2[r][3] + bs0.w;
        s1.x += acc2[r][4] + bs1.x; s1.y += acc2[r][5] + bs1.y;
        s1.z += acc2[r][6] + bs1.z; s1.w += acc2[r][7] + bs1.w;
        *(float4*)sp       = s0;
        *(float4*)(sp + 4) = s1;

        const float* xp = x + (size_t)row * 128 + c0;
        const float4 x0 = *(const float4*)xp;
        const float4 x1 = *(const float4*)(xp + 4);
        float4 o0, o1;
        o0.x = (x0.x + acc2[r][8]  + bo0.x) * SQRT_HALF;
        o0.y = (x0.y + acc2[r][9]  + bo0.y) * SQRT_HALF;
        o0.z = (x0.z + acc2[r][10] + bo0.z) * SQRT_HALF;
        o0.w = (x0.w + acc2[r][11] + bo0.w) * SQRT_HALF;
        o1.x = (x1.x + acc2[r][12] + bo1.x) * SQRT_HALF;
        o1.y = (x1.y + acc2[r][13] + bo1.y) * SQRT_HALF;
        o1.z = (x1.z + acc2[r][14] + bo1.z) * SQRT_HALF;
        o1.w = (x1.w + acc2[r][15] + bo1.w) * SQRT_HALF;
        *(float4*)(xn + (size_t)row * 128 + c0)     = o0;
        *(float4*)(xn + (size_t)row * 128 + c0 + 4) = o1;
    }
}

// ------------------------------------------------------------- final stack ---
// y = relu(skips); h = relu(y@W1 + b1); out = h@W2 + b2
__launch_bounds__(256, 2)
__global__ void final_k(const float* __restrict__ skips,
                        const float* __restrict__ W1, const float* __restrict__ b1,
                        const float* __restrict__ W2, const float* __restrict__ b2,
                        float* __restrict__ out)
{
    __shared__ __align__(16) float A[16][68];
    __shared__ __align__(16) float Bm[16 * 256];
    __shared__ __align__(16) float zt[128][68];
    const int tid  = threadIdx.x;
    const int tn   = tid & 15;
    const int tm   = tid >> 4;
    const int arow = tid >> 2;
    const int ak4  = (tid & 3) * 4;
    const int r0   = blockIdx.x * 64;
    const int c0   = tn * 8;

    // stage 1: h = relu(relu(skips) @ W1 + b1), K=128, N=128
    float acc[4][8];
#pragma unroll
    for (int r = 0; r < 4; ++r)
#pragma unroll
        for (int j = 0; j < 8; ++j) acc[r][j] = 0.f;

    float4 av, bv0, bv1;
    auto load1 = [&](int ch) {
        av = *(const float4*)(skips + (size_t)(r0 + arow) * 128 + ch * 16 + ak4);
        av.x = fmaxf(av.x, 0.f); av.y = fmaxf(av.y, 0.f);
        av.z = fmaxf(av.z, 0.f); av.w = fmaxf(av.w, 0.f);
        bv0 = *(const float4*)(W1 + ch * 2048 + tid * 4);
        bv1 = *(const float4*)(W1 + ch * 2048 + 1024 + tid * 4);
    };
    load1(0);
    for (int ch = 0; ch < 8; ++ch) {
        __syncthreads();
        A[ak4 + 0][arow] = av.x; A[ak4 + 1][arow] = av.y;
        A[ak4 + 2][arow] = av.z; A[ak4 + 3][arow] = av.w;
        *(float4*)(Bm + tid * 4) = bv0;
        *(float4*)(Bm + 1024 + tid * 4) = bv1;
        __syncthreads();
        if (ch < 7) load1(ch + 1);
#pragma unroll
        for (int k = 0; k < 16; ++k) {
            const float4 a4 = *(const float4*)&A[k][tm * 4];
            const float4 b0 = *(const float4*)&Bm[k * 128 + tn * 8];
            const float4 b1v = *(const float4*)&Bm[k * 128 + tn * 8 + 4];
            const float aa[4]  = {a4.x, a4.y, a4.z, a4.w};
            const float bb8[8] = {b0.x, b0.y, b0.z, b0.w, b1v.x, b1v.y, b1v.z, b1v.w};
#pragma unroll
            for (int r = 0; r < 4; ++r)
#pragma unroll
                for (int j = 0; j < 8; ++j) acc[r][j] += aa[r] * bb8[j];
        }
    }
#pragma unroll
    for (int r = 0; r < 4; ++r)
#pragma unroll
        for (int j = 0; j < 8; ++j) {
            float h = acc[r][j] + b1[c0 + j];
            zt[c0 + j][tm * 4 + r] = fmaxf(h, 0.f);
        }

    // stage 2: out = h @ W2 + b2, K=128, N=256
    float acc2[4][16];
#pragma unroll
    for (int r = 0; r < 4; ++r)
#pragma unroll
        for (int j = 0; j < 16; ++j) acc2[r][j] = 0.f;
    float4 bv[4];
    auto load2 = [&](int ch) {
#pragma unroll
        for (int j = 0; j < 4; ++j)
            bv[j] = *(const float4*)(W2 + ch * 4096 + j * 1024 + tid * 4);
    };
    load2(0);
    for (int ch = 0; ch < 8; ++ch) {
        __syncthreads();
#pragma unroll
        for (int j = 0; j < 4; ++j)
            *(float4*)(Bm + j * 1024 + tid * 4) = bv[j];
        __syncthreads();
        if (ch < 7) load2(ch + 1);
#pragma unroll
        for (int k = 0; k < 16; ++k) {
            const float4 a4 = *(const float4*)&zt[ch * 16 + k][tm * 4];
            const float4 b0 = *(const float4*)&Bm[k * 256 + tn * 8];
            const float4 b1v = *(const float4*)&Bm[k * 256 + tn * 8 + 4];
            const float4 b2v = *(const float4*)&Bm[k * 256 + tn * 8 + 128];
            const float4 b3v = *(const float4*)&Bm[k * 256 + tn * 8 + 132];
            const float aa[4]   = {a4.x, a4.y, a4.z, a4.w};
            const float bb16[16] = {b0.x, b0.y, b0.z, b0.w, b1v.x, b1v.y, b1v.z, b1v.w,
                                    b2v.x, b2v.y, b2v.z, b2v.w, b3v.x, b3v.y, b3v.z, b3v.w};
#pragma unroll
            for (int r = 0; r < 4; ++r)
#pragma unroll
                for (int j = 0; j < 16; ++j) acc2[r][j] += aa[r] * bb16[j];
        }
    }
    const float4 fb0 = *(const float4*)(b2 + c0);
    const float4 fb1 = *(const float4*)(b2 + c0 + 4);
    const float4 fb2 = *(const float4*)(b2 + 128 + c0);
    const float4 fb3 = *(const float4*)(b2 + 128 + c0 + 4);
#pragma unroll
    for (int r = 0; r < 4; ++r) {
        const int row = r0 + tm * 4 + r;
        float* op = out + (size_t)row * 256;
        float4 o0 = {acc2[r][0] + fb0.x, acc2[r][1] + fb0.y, acc2[r][2] + fb0.z, acc2[r][3] + fb0.w};
        float4 o1 = {acc2[r][4] + fb1.x, acc2[r][5] + fb1.y, acc2[r][6] + fb1.z, acc2[r][7] + fb1.w};
        float4 o2 = {acc2[r][8] + fb2.x, acc2[r][9] + fb2.y, acc2[r][10] + fb2.z, acc2[r][11] + fb2.w};
        float4 o3 = {acc2[r][12] + fb3.x, acc2[r][13] + fb3.y, acc2[r][14] + fb3.z, acc2[r][15] + fb3.w};
        *(float4*)(op + c0)           = o0;
        *(float4*)(op + c0 + 4)       = o1;
        *(float4*)(op + 128 + c0)     = o2;
        *(float4*)(op + 128 + c0 + 4) = o3;
    }
}

// ---------------------------------------------------------------- launcher ---
extern "C" void kernel_launch(void* const* d_in, const int* in_sizes, int n_in,
                              void* d_out, int out_size, void* d_ws, size_t ws_size,
                              hipStream_t stream)
{
    const float* inputs  = (const float*)d_in[0];
    const float* c       = (const float*)d_in[1];
    const float* up_w0   = (const float*)d_in[2];
    const float* up_w1   = (const float*)d_in[3];
    const float* up_w2   = (const float*)d_in[4];
    const float* first_w = (const float*)d_in[5];
    const float* first_b = (const float*)d_in[6];
    const float* Wd      = (const float*)d_in[7];
    const float* bd      = (const float*)d_in[8];
    const float* Wc      = (const float*)d_in[9];
    const float* Ws      = (const float*)d_in[10];
    const float* bs      = (const float*)d_in[11];
    const float* Wo      = (const float*)d_in[12];
    const float* bo_     = (const float*)d_in[13];
    const float* f1w     = (const float*)d_in[14];
    const float* f1b     = (const float*)d_in[15];
    const float* f2w     = (const float*)d_in[16];
    const float* f2b     = (const float*)d_in[17];

    float* ws    = (float*)d_ws;
    float* cond  = ws;                                  // [B,T,80]  10,485,760 f
    float* skips = ws + (size_t)BB * TA * MELSC;        // [M,128]   16,777,216 f
    // upsample temps live inside the (not-yet-initialized) skips region
    float* tmp1  = skips;                               //  163,840 f
    float* tmp2  = skips + 163840;                      // 1,310,720 f

    // x ping-pongs through the two halves of d_out (exactly 2 * M * 128 floats)
    float* xa = (float*)d_out;
    float* xb = xa + (size_t)MROWS * RCH;

    const int P = BB * MELSC;   // 640 (b,mel) rows
    upsample_k<<<(P * 256  + 255) / 256, 256, 0, stream>>>(c,    tmp1, up_w0, 64,   256,  4, 8,  5,  P, 0);
    upsample_k<<<(P * 2048 + 255) / 256, 256, 0, stream>>>(tmp1, tmp2, up_w1, 256,  2048, 8, 16, 11, P, 0);
    upsample_k<<<(P * TA   + 255) / 256, 256, 0, stream>>>(tmp2, cond, up_w2, 2048, TA,   8, 16, 11, P, 1);

    first_k<<<MROWS / 64, 256, 0, stream>>>(inputs, first_w, first_b, xa, skips);

    const float* xs = xa;
    float*       xd = xb;
    for (int i = 0; i < NBLK; ++i) {
        const int d = 1 << (i % 10);
        block_k<<<MROWS / 64, 256, 0, stream>>>(
            xs, xd, cond, skips,
            Wd + (size_t)i * 3 * 128 * 256, bd + i * 256,
            Wc + (size_t)i * 80 * 256,
            Ws + (size_t)i * 128 * 128, bs + i * 128,
            Wo + (size_t)i * 128 * 128, bo_ + i * 128, d);
        float* t = (float*)xs; xs = xd; xd = t;
    }

    final_k<<<MROWS / 64, 256, 0, stream>>>(skips, f1w, f1b, f2w, f2b, (float*)d_out);
}

// Round 7
// 6383.773 us; speedup vs baseline: 2.5457x; 2.5457x over previous
//
#include <hip/hip_runtime.h>
#include <hip/hip_bf16.h>
#include <math.h>

// WaveNet forward. B=8, T=16384, R=128, G=256, S=128, K=3, 20 blocks.
// Fast path: bf16x3 (hi/lo split) MFMA for the residual blocks, ~fp32 accuracy.
#define TA    16384
#define NBLK  20
#define RCH   128
#define GCH   256
#define MELSC 80
#define CPAD  96                 // cond K padded to 96 (3 chunks of 32)
#define KTOT  480                // 12*32 (3 taps x 128) + 96 (cond)
#define BB    8
#define MROWS (BB * TA)          // 131072 rows
#define SQRT_HALF 0.70710678118654752440f

typedef __attribute__((ext_vector_type(8))) short          bf16x8;
typedef __attribute__((ext_vector_type(4))) float          f32x4;
typedef __attribute__((ext_vector_type(4))) unsigned int   u32x4;
typedef __attribute__((ext_vector_type(8))) unsigned short u16x8;

__device__ __forceinline__ unsigned short bf16_rn(float x) {
    union { float f; unsigned int u; } v; v.f = x;
    unsigned int r = v.u + 0x7fffu + ((v.u >> 16) & 1u);
    return (unsigned short)(r >> 16);
}
__device__ __forceinline__ float bf16_tf(unsigned short h) {
    union { unsigned int u; float f; } v; v.u = ((unsigned int)h) << 16; return v.f;
}

// ---------------------------------------------------------------- upsample ---
__global__ void upsample_k(const float* __restrict__ in, float* __restrict__ out,
                           const float* __restrict__ w,
                           int Tin, int Tout, int s, int k, int pad_a,
                           int P, int transposed)
{
    int idx = blockIdx.x * blockDim.x + threadIdx.x;
    if (idx >= P * Tout) return;
    int p = idx / Tout;
    int t = idx - p * Tout;
    float acc = 0.f;
    for (int j = 0; j < k; ++j) {
        int q = t + j - pad_a;
        if (q >= 0 && (q % s) == 0) {
            int i = q / s;
            if (i < Tin) acc += w[j] * in[p * Tin + i];
        }
    }
    if (!transposed) {
        out[p * Tout + t] = acc;
    } else {
        int b = p / MELSC;
        int m = p - b * MELSC;
        out[((size_t)b * Tout + t) * MELSC + m] = acc;
    }
}

// final upsample stage writing cond as bf16 hi/lo [B][T][96] (zero-padded mels)
__global__ void upsample_cond_k(const float* __restrict__ in,
                                unsigned short* __restrict__ oh,
                                unsigned short* __restrict__ ol,
                                const float* __restrict__ w,
                                int Tin, int s, int k, int pad_a)
{
    int idx = blockIdx.x * blockDim.x + threadIdx.x;
    if (idx >= BB * CPAD * TA) return;
    int m  = idx % CPAD;
    int t2 = idx / CPAD;
    int t  = t2 % TA;
    int b  = t2 / TA;
    float acc = 0.f;
    if (m < MELSC) {
        const float* inp = in + ((size_t)b * MELSC + m) * Tin;
        for (int j = 0; j < k; ++j) {
            int q = t + j - pad_a;
            if (q >= 0 && (q % s) == 0) {
                int i = q / s;
                if (i < Tin) acc += w[j] * inp[i];
            }
        }
    }
    unsigned short h = bf16_rn(acc);
    oh[idx] = h;
    ol[idx] = bf16_rn(acc - bf16_tf(h));
}

// ------------------------------------------------------- weight prep (once) ---
// W1T[blk][col'][480] : col' = w*64 + n*16 + i ; gc = n<2 ? 32w+n*16+i : 128+32w+(n-2)*16+i
// k: 0..383 = tap*128+ch (Wd), 384..463 = cond (Wc), 464..479 = 0
__global__ void prep_w1(const float* __restrict__ Wd, const float* __restrict__ Wc,
                        unsigned short* __restrict__ w1h, unsigned short* __restrict__ w1l)
{
    int idx = blockIdx.x * 256 + threadIdx.x;
    if (idx >= NBLK * 256 * KTOT) return;
    int k    = idx % KTOT;
    int t    = idx / KTOT;
    int colp = t % 256;
    int blk  = t / 256;
    int w = colp >> 6, nn = (colp >> 4) & 3, i = colp & 15;
    int gc = (nn < 2) ? (32 * w + nn * 16 + i) : (128 + 32 * w + (nn - 2) * 16 + i);
    float val = 0.f;
    if (k < 384) {
        int tap = k >> 7, ch = k & 127;
        val = Wd[((size_t)(blk * 3 + tap) * 128 + ch) * 256 + gc];
    } else if (k - 384 < MELSC) {
        val = Wc[((size_t)blk * MELSC + (k - 384)) * 256 + gc];
    }
    unsigned short h = bf16_rn(val);
    w1h[idx] = h;
    w1l[idx] = bf16_rn(val - bf16_tf(h));
}

// W2T[blk][col'][128] : n<2 -> Ws col (skip), n>=2 -> Wo col (xo); k = z channel
__global__ void prep_w2(const float* __restrict__ Ws, const float* __restrict__ Wo,
                        unsigned short* __restrict__ w2h, unsigned short* __restrict__ w2l)
{
    int idx = blockIdx.x * 256 + threadIdx.x;
    if (idx >= NBLK * 256 * 128) return;
    int k    = idx & 127;
    int t    = idx >> 7;
    int colp = t % 256;
    int blk  = t / 256;
    int w = colp >> 6, nn = (colp >> 4) & 3, i = colp & 15;
    float val;
    if (nn < 2) { int sc = 32 * w + nn * 16 + i;      val = Ws[((size_t)blk * 128 + k) * 128 + sc]; }
    else        { int oc = 32 * w + (nn - 2) * 16 + i; val = Wo[((size_t)blk * 128 + k) * 128 + oc]; }
    unsigned short h = bf16_rn(val);
    w2h[idx] = h;
    w2l[idx] = bf16_rn(val - bf16_tf(h));
}

// ------------------------------------------------- first conv (bf16 x out) ---
__launch_bounds__(256, 2)
__global__ void first_k_bf(const float* __restrict__ inp,   // [M,256]
                           const float* __restrict__ W,     // [256][128]
                           const float* __restrict__ bias,  // [128]
                           unsigned short* __restrict__ xh, // [M,128]
                           unsigned short* __restrict__ xl,
                           float* __restrict__ skips)       // [M,128]
{
    __shared__ __align__(16) float A[16][68];
    __shared__ __align__(16) float Bm[16 * 128];
    const int tid  = threadIdx.x;
    const int tn   = tid & 15;
    const int tm   = tid >> 4;
    const int arow = tid >> 2;
    const int ak4  = (tid & 3) * 4;
    const int r0   = blockIdx.x * 64;

    float acc[4][8];
#pragma unroll
    for (int r = 0; r < 4; ++r)
#pragma unroll
        for (int j = 0; j < 8; ++j) acc[r][j] = 0.f;

    float4 av, bv0, bv1;
    auto loadch = [&](int ch) {
        av  = *(const float4*)(inp + (size_t)(r0 + arow) * 256 + ch * 16 + ak4);
        bv0 = *(const float4*)(W + ch * 2048 + tid * 4);
        bv1 = *(const float4*)(W + ch * 2048 + 1024 + tid * 4);
    };
    loadch(0);
    for (int ch = 0; ch < 16; ++ch) {
        __syncthreads();
        A[ak4 + 0][arow] = av.x; A[ak4 + 1][arow] = av.y;
        A[ak4 + 2][arow] = av.z; A[ak4 + 3][arow] = av.w;
        *(float4*)(Bm + tid * 4) = bv0;
        *(float4*)(Bm + 1024 + tid * 4) = bv1;
        __syncthreads();
        if (ch < 15) loadch(ch + 1);
#pragma unroll
        for (int k = 0; k < 16; ++k) {
            const float4 a4 = *(const float4*)&A[k][tm * 4];
            const float4 b0 = *(const float4*)&Bm[k * 128 + tn * 8];
            const float4 b1 = *(const float4*)&Bm[k * 128 + tn * 8 + 4];
            const float aa[4]  = {a4.x, a4.y, a4.z, a4.w};
            const float bb8[8] = {b0.x, b0.y, b0.z, b0.w, b1.x, b1.y, b1.z, b1.w};
#pragma unroll
            for (int r = 0; r < 4; ++r)
#pragma unroll
                for (int j = 0; j < 8; ++j) acc[r][j] += aa[r] * bb8[j];
        }
    }
    const int c0 = tn * 8;
    const float4 bi0 = *(const float4*)(bias + c0);
    const float4 bi1 = *(const float4*)(bias + c0 + 4);
    const float bb[8] = {bi0.x, bi0.y, bi0.z, bi0.w, bi1.x, bi1.y, bi1.z, bi1.w};
#pragma unroll
    for (int r = 0; r < 4; ++r) {
        const size_t row = r0 + tm * 4 + r;
        u16x8 vh, vl;
#pragma unroll
        for (int j = 0; j < 8; ++j) {
            float v = acc[r][j] + bb[j];
            unsigned short h = bf16_rn(v);
            vh[j] = h;
            vl[j] = bf16_rn(v - bf16_tf(h));
        }
        *(u16x8*)(xh + row * 128 + c0) = vh;
        *(u16x8*)(xl + row * 128 + c0) = vl;
        float4 z4 = {0.f, 0.f, 0.f, 0.f};
        *(float4*)(skips + row * 128 + c0)     = z4;
        *(float4*)(skips + row * 128 + c0 + 4) = z4;
    }
}

// ------------------------------------------------ residual block via MFMA ---
// 64 rows x 256 cols tile, 4 waves; wave w owns cols' [64w,64w+64).
// bf16x3: D = Ah*Bh + Ah*Bl + Al*Bh (~fp32 accuracy).
__launch_bounds__(256, 3)
__global__ void block_k_mfma(
    const unsigned short* __restrict__ xh, const unsigned short* __restrict__ xl,
    unsigned short* __restrict__ xnh, unsigned short* __restrict__ xnl,
    const unsigned short* __restrict__ ch_, const unsigned short* __restrict__ cl_, // [B][T][96]
    float* __restrict__ skips,
    const unsigned short* __restrict__ w1h, const unsigned short* __restrict__ w1l, // [256][480]
    const unsigned short* __restrict__ w2h, const unsigned short* __restrict__ w2l, // [256][128]
    const float* __restrict__ bd, const float* __restrict__ bs,
    const float* __restrict__ bo, int d)
{
    // pitch 40 shorts (80B): bank-conflict-free fragment reads (2-way max)
    __shared__ __align__(16) unsigned short As[2][64 * 40];
    __shared__ __align__(16) unsigned short Bs[2][256 * 40];

    const int tid = threadIdx.x;
    const int wv  = tid >> 6;
    const int ln  = tid & 63;
    const int l15 = ln & 15;
    const int l4  = ln >> 4;
    const int r0  = blockIdx.x * 64;
    const int b   = r0 / TA;
    const int t0  = r0 - b * TA;

    const int arow = tid >> 2;       // A staging row 0..63
    const int asl  = tid & 3;        // A staging k-slot

    f32x4 acc[4][4];
#pragma unroll
    for (int m = 0; m < 4; ++m)
#pragma unroll
        for (int n = 0; n < 4; ++n) acc[m][n] = (f32x4){0.f, 0.f, 0.f, 0.f};

    // ---- stage 1: g = [x taps | cond] @ W1T, K = 15 chunks of 32
    for (int c = 0; c < 15; ++c) {
        __syncthreads();
        {   // A tile
            const int koff = asl * 8;
            u32x4 vh, vl;
            if (c < 12) {
                const int tap = c >> 2, kc = (c & 3) * 32;
                const int ts = t0 + arow - (2 - tap) * d;
                if (ts >= 0) {
                    const size_t g = ((size_t)(b * TA + ts)) * 128 + kc + koff;
                    vh = *(const u32x4*)(xh + g);
                    vl = *(const u32x4*)(xl + g);
                } else { vh = (u32x4){0, 0, 0, 0}; vl = vh; }
            } else {
                const int kc = (c - 12) * 32;
                const size_t g = ((size_t)(b * TA + t0 + arow)) * CPAD + kc + koff;
                vh = *(const u32x4*)(ch_ + g);
                vl = *(const u32x4*)(cl_ + g);
            }
            *(u32x4*)&As[0][arow * 40 + koff] = vh;
            *(u32x4*)&As[1][arow * 40 + koff] = vl;
        }
        {   // B tile (col = tid)
            const unsigned short* s1 = w1h + (size_t)tid * KTOT + c * 32;
            const unsigned short* s2 = w1l + (size_t)tid * KTOT + c * 32;
#pragma unroll
            for (int j = 0; j < 4; ++j) {
                *(u32x4*)&Bs[0][tid * 40 + j * 8] = *(const u32x4*)(s1 + j * 8);
                *(u32x4*)&Bs[1][tid * 40 + j * 8] = *(const u32x4*)(s2 + j * 8);
            }
        }
        __syncthreads();
        bf16x8 ah[4], al[4];
#pragma unroll
        for (int m = 0; m < 4; ++m) {
            ah[m] = *(const bf16x8*)&As[0][(m * 16 + l15) * 40 + l4 * 8];
            al[m] = *(const bf16x8*)&As[1][(m * 16 + l15) * 40 + l4 * 8];
        }
#pragma unroll
        for (int n = 0; n < 4; ++n) {
            const bf16x8 bh = *(const bf16x8*)&Bs[0][(wv * 64 + n * 16 + l15) * 40 + l4 * 8];
            const bf16x8 bl = *(const bf16x8*)&Bs[1][(wv * 64 + n * 16 + l15) * 40 + l4 * 8];
#pragma unroll
            for (int m = 0; m < 4; ++m) {
                acc[m][n] = __builtin_amdgcn_mfma_f32_16x16x32_bf16(ah[m], bh, acc[m][n], 0, 0, 0);
                acc[m][n] = __builtin_amdgcn_mfma_f32_16x16x32_bf16(ah[m], bl, acc[m][n], 0, 0, 0);
                acc[m][n] = __builtin_amdgcn_mfma_f32_16x16x32_bf16(al[m], bh, acc[m][n], 0, 0, 0);
            }
        }
    }

    // ---- GLU: a = acc[.][0,1], b = acc[.][2,3] (cols permuted so pairs are local)
    float z[4][2][4];
#pragma unroll
    for (int n = 0; n < 2; ++n) {
        const int gca = 32 * wv + n * 16 + l15;
        const float ba = bd[gca];
        const float bg = bd[128 + gca];
#pragma unroll
        for (int m = 0; m < 4; ++m)
#pragma unroll
            for (int r = 0; r < 4; ++r) {
                const float a = acc[m][n][r] + ba;
                const float g = acc[m][n + 2][r] + bg;
                const float t  = 1.f - 2.f / (__expf(2.f * fabsf(a)) + 1.f);  // tanh(|a|), overflow-safe
                const float th = copysignf(t, a);
                const float sg = 1.f / (1.f + __expf(-g));
                z[m][n][r] = th * sg;
            }
    }

    // ---- stage 2: [skip | xo] = z @ W2T, K = 4 chunks of 32 (z streamed via As)
    f32x4 acc2[4][4];
#pragma unroll
    for (int m = 0; m < 4; ++m)
#pragma unroll
        for (int n = 0; n < 4; ++n) acc2[m][n] = (f32x4){0.f, 0.f, 0.f, 0.f};

    for (int c = 0; c < 4; ++c) {
        __syncthreads();
        if (wv == c) {  // owner wave writes its z chunk (zch = 32c + zl)
#pragma unroll
            for (int n = 0; n < 2; ++n) {
                const int zl = n * 16 + l15;
#pragma unroll
                for (int m = 0; m < 4; ++m)
#pragma unroll
                    for (int r = 0; r < 4; ++r) {
                        const int row = m * 16 + l4 * 4 + r;
                        const float v = z[m][n][r];
                        const unsigned short h = bf16_rn(v);
                        As[0][row * 40 + zl] = h;
                        As[1][row * 40 + zl] = bf16_rn(v - bf16_tf(h));
                    }
            }
        }
        {   // B2 tile
            const unsigned short* s1 = w2h + (size_t)tid * 128 + c * 32;
            const unsigned short* s2 = w2l + (size_t)tid * 128 + c * 32;
#pragma unroll
            for (int j = 0; j < 4; ++j) {
                *(u32x4*)&Bs[0][tid * 40 + j * 8] = *(const u32x4*)(s1 + j * 8);
                *(u32x4*)&Bs[1][tid * 40 + j * 8] = *(const u32x4*)(s2 + j * 8);
            }
        }
        __syncthreads();
        bf16x8 ah[4], al[4];
#pragma unroll
        for (int m = 0; m < 4; ++m) {
            ah[m] = *(const bf16x8*)&As[0][(m * 16 + l15) * 40 + l4 * 8];
            al[m] = *(const bf16x8*)&As[1][(m * 16 + l15) * 40 + l4 * 8];
        }
#pragma unroll
        for (int n = 0; n < 4; ++n) {
            const bf16x8 bh = *(const bf16x8*)&Bs[0][(wv * 64 + n * 16 + l15) * 40 + l4 * 8];
            const bf16x8 bl = *(const bf16x8*)&Bs[1][(wv * 64 + n * 16 + l15) * 40 + l4 * 8];
#pragma unroll
            for (int m = 0; m < 4; ++m) {
                acc2[m][n] = __builtin_amdgcn_mfma_f32_16x16x32_bf16(ah[m], bh, acc2[m][n], 0, 0, 0);
                acc2[m][n] = __builtin_amdgcn_mfma_f32_16x16x32_bf16(ah[m], bl, acc2[m][n], 0, 0, 0);
                acc2[m][n] = __builtin_amdgcn_mfma_f32_16x16x32_bf16(al[m], bh, acc2[m][n], 0, 0, 0);
            }
        }
    }

    // ---- epilogue
#pragma unroll
    for (int n = 0; n < 2; ++n) {
        const int sc = 32 * wv + n * 16 + l15;
        const float bsv = bs[sc];
#pragma unroll
        for (int m = 0; m < 4; ++m)
#pragma unroll
            for (int r = 0; r < 4; ++r) {
                const size_t row = (size_t)r0 + m * 16 + l4 * 4 + r;
                skips[row * 128 + sc] += acc2[m][n][r] + bsv;
            }
    }
#pragma unroll
    for (int n = 0; n < 2; ++n) {
        const int oc = 32 * wv + n * 16 + l15;
        const float bov = bo[oc];
#pragma unroll
        for (int m = 0; m < 4; ++m)
#pragma unroll
            for (int r = 0; r < 4; ++r) {
                const size_t g = ((size_t)r0 + m * 16 + l4 * 4 + r) * 128 + oc;
                const float xv = bf16_tf(xh[g]) + bf16_tf(xl[g]);
                const float xn = (xv + acc2[m][n + 2][r] + bov) * SQRT_HALF;
                const unsigned short h = bf16_rn(xn);
                xnh[g] = h;
                xnl[g] = bf16_rn(xn - bf16_tf(h));
            }
    }
}

// ------------------------------- fallback fp32 kernels (proven in round 4) ---
__launch_bounds__(256, 2)
__global__ void first_k(const float* __restrict__ inp, const float* __restrict__ W,
                        const float* __restrict__ bias, float* __restrict__ x,
                        float* __restrict__ skips)
{
    __shared__ __align__(16) float A[16][68];
    __shared__ __align__(16) float Bm[16 * 128];
    const int tid = threadIdx.x, tn = tid & 15, tm = tid >> 4;
    const int arow = tid >> 2, ak4 = (tid & 3) * 4, r0 = blockIdx.x * 64;
    float acc[4][8];
#pragma unroll
    for (int r = 0; r < 4; ++r)
#pragma unroll
        for (int j = 0; j < 8; ++j) acc[r][j] = 0.f;
    float4 av, bv0, bv1;
    auto loadch = [&](int ch) {
        av  = *(const float4*)(inp + (size_t)(r0 + arow) * 256 + ch * 16 + ak4);
        bv0 = *(const float4*)(W + ch * 2048 + tid * 4);
        bv1 = *(const float4*)(W + ch * 2048 + 1024 + tid * 4);
    };
    loadch(0);
    for (int ch = 0; ch < 16; ++ch) {
        __syncthreads();
        A[ak4 + 0][arow] = av.x; A[ak4 + 1][arow] = av.y;
        A[ak4 + 2][arow] = av.z; A[ak4 + 3][arow] = av.w;
        *(float4*)(Bm + tid * 4) = bv0;
        *(float4*)(Bm + 1024 + tid * 4) = bv1;
        __syncthreads();
        if (ch < 15) loadch(ch + 1);
#pragma unroll
        for (int k = 0; k < 16; ++k) {
            const float4 a4 = *(const float4*)&A[k][tm * 4];
            const float4 b0 = *(const float4*)&Bm[k * 128 + tn * 8];
            const float4 b1 = *(const float4*)&Bm[k * 128 + tn * 8 + 4];
            const float aa[4]  = {a4.x, a4.y, a4.z, a4.w};
            const float bb8[8] = {b0.x, b0.y, b0.z, b0.w, b1.x, b1.y, b1.z, b1.w};
#pragma unroll
            for (int r = 0; r < 4; ++r)
#pragma unroll
                for (int j = 0; j < 8; ++j) acc[r][j] += aa[r] * bb8[j];
        }
    }
    const int c0 = tn * 8;
    const float4 bi0 = *(const float4*)(bias + c0);
    const float4 bi1 = *(const float4*)(bias + c0 + 4);
#pragma unroll
    for (int r = 0; r < 4; ++r) {
        const int row = r0 + tm * 4 + r;
        float4 o0 = {acc[r][0] + bi0.x, acc[r][1] + bi0.y, acc[r][2] + bi0.z, acc[r][3] + bi0.w};
        float4 o1 = {acc[r][4] + bi1.x, acc[r][5] + bi1.y, acc[r][6] + bi1.z, acc[r][7] + bi1.w};
        *(float4*)(x + (size_t)row * 128 + c0)     = o0;
        *(float4*)(x + (size_t)row * 128 + c0 + 4) = o1;
        float4 z4 = {0.f, 0.f, 0.f, 0.f};
        *(float4*)(skips + (size_t)row * 128 + c0)     = z4;
        *(float4*)(skips + (size_t)row * 128 + c0 + 4) = z4;
    }
}

__launch_bounds__(256, 2)
__global__ void block_k(const float* __restrict__ x, float* __restrict__ xn,
                        const float* __restrict__ cond, float* __restrict__ skips,
                        const float* __restrict__ Wd, const float* __restrict__ bd,
                        const float* __restrict__ Wc,
                        const float* __restrict__ Ws, const float* __restrict__ bs,
                        const float* __restrict__ Wo, const float* __restrict__ bo,
                        int d)
{
    __shared__ __align__(16) float A[16][68];
    __shared__ __align__(16) float Bm[16 * 256];
    __shared__ __align__(16) float zt[128][68];
    const int tid = threadIdx.x, tn = tid & 15, tm = tid >> 4;
    const int arow = tid >> 2, ak4 = (tid & 3) * 4, r0 = blockIdx.x * 64;
    const int b = r0 / TA, t0 = r0 - b * TA;
    const float* xb = x + (size_t)b * TA * RCH;
    float acc[4][16];
#pragma unroll
    for (int r = 0; r < 4; ++r)
#pragma unroll
        for (int j = 0; j < 16; ++j) acc[r][j] = 0.f;
    float4 av, bv[4];
    auto loadch = [&](int ch) {
        if (ch < 24) {
            const int tap = ch >> 3, kc = (ch & 7) * 16;
            const int ts = t0 + arow - (2 - tap) * d;
            if (ts >= 0) av = *(const float4*)(xb + (size_t)ts * RCH + kc + ak4);
            else         av = make_float4(0.f, 0.f, 0.f, 0.f);
            const float* bsrc = Wd + ch * (16 * 256);
#pragma unroll
            for (int j = 0; j < 4; ++j) bv[j] = *(const float4*)(bsrc + j * 1024 + tid * 4);
        } else {
            const int kc = (ch - 24) * 16;
            av = *(const float4*)(cond + ((size_t)b * TA + (t0 + arow)) * MELSC + kc + ak4);
            const float* bsrc = Wc + (ch - 24) * (16 * 256);
#pragma unroll
            for (int j = 0; j < 4; ++j) bv[j] = *(const float4*)(bsrc + j * 1024 + tid * 4);
        }
    };
    loadch(0);
    for (int ch = 0; ch < 29; ++ch) {
        __syncthreads();
        A[ak4 + 0][arow] = av.x; A[ak4 + 1][arow] = av.y;
        A[ak4 + 2][arow] = av.z; A[ak4 + 3][arow] = av.w;
#pragma unroll
        for (int j = 0; j < 4; ++j) *(float4*)(Bm + j * 1024 + tid * 4) = bv[j];
        __syncthreads();
        if (ch < 28) loadch(ch + 1);
#pragma unroll
        for (int k = 0; k < 16; ++k) {
            const float4 a4 = *(const float4*)&A[k][tm * 4];
            const float4 b0 = *(const float4*)&Bm[k * 256 + tn * 8];
            const float4 b1 = *(const float4*)&Bm[k * 256 + tn * 8 + 4];
            const float4 b2 = *(const float4*)&Bm[k * 256 + tn * 8 + 128];
            const float4 b3 = *(const float4*)&Bm[k * 256 + tn * 8 + 132];
            const float aa[4]   = {a4.x, a4.y, a4.z, a4.w};
            const float bb16[16] = {b0.x, b0.y, b0.z, b0.w, b1.x, b1.y, b1.z, b1.w,
                                    b2.x, b2.y, b2.z, b2.w, b3.x, b3.y, b3.z, b3.w};
#pragma unroll
            for (int r = 0; r < 4; ++r)
#pragma unroll
                for (int j = 0; j < 16; ++j) acc[r][j] += aa[r] * bb16[j];
        }
    }
    const int c0 = tn * 8;
#pragma unroll
    for (int r = 0; r < 4; ++r)
#pragma unroll
        for (int j = 0; j < 8; ++j) {
            const float a = acc[r][j] + bd[c0 + j];
            const float g = acc[r][8 + j] + bd[128 + c0 + j];
            zt[c0 + j][tm * 4 + r] = tanhf(a) * (1.f / (1.f + expf(-g)));
        }
    float acc2[4][16];
#pragma unroll
    for (int r = 0; r < 4; ++r)
#pragma unroll
        for (int j = 0; j < 16; ++j) acc2[r][j] = 0.f;
    const int half = tid >> 7, st = tid & 127;
    const float* W2 = half ? Wo : Ws;
    float4 b2v[4];
    auto loadch2 = [&](int ch) {
#pragma unroll
        for (int j = 0; j < 4; ++j) {
            const int f = j * 512 + st * 4, kk = f >> 7, cc = f & 127;
            b2v[j] = *(const float4*)(W2 + (ch * 16 + kk) * 128 + cc);
        }
    };
    loadch2(0);
    for (int ch = 0; ch < 8; ++ch) {
        __syncthreads();
#pragma unroll
        for (int j = 0; j < 4; ++j) {
            const int f = j * 512 + st * 4, kk = f >> 7, cc = f & 127;
            *(float4*)(Bm + kk * 256 + half * 128 + cc) = b2v[j];
        }
        __syncthreads();
        if (ch < 7) loadch2(ch + 1);
#pragma unroll
        for (int k = 0; k < 16; ++k) {
            const float4 a4 = *(const float4*)&zt[ch * 16 + k][tm * 4];
            const float4 b0 = *(const float4*)&Bm[k * 256 + tn * 8];
            const float4 b1 = *(const float4*)&Bm[k * 256 + tn * 8 + 4];
            const float4 b2 = *(const float4*)&Bm[k * 256 + tn * 8 + 128];
            const float4 b3 = *(const float4*)&Bm[k * 256 + tn * 8 + 132];
            const float aa[4]   = {a4.x, a4.y, a4.z, a4.w};
            const float bb16[16] = {b0.x, b0.y, b0.z, b0.w, b1.x, b1.y, b1.z, b1.w,
                                    b2.x, b2.y, b2.z, b2.w, b3.x, b3.y, b3.z, b3.w};
#pragma unroll
            for (int r = 0; r < 4; ++r)
#pragma unroll
                for (int j = 0; j < 16; ++j) acc2[r][j] += aa[r] * bb16[j];
        }
    }
    const float4 bs0 = *(const float4*)(bs + c0);
    const float4 bs1 = *(const float4*)(bs + c0 + 4);
    const float4 bo0 = *(const float4*)(bo + c0);
    const float4 bo1 = *(const float4*)(bo + c0 + 4);
#pragma unroll
    for (int r = 0; r < 4; ++r) {
        const int row = r0 + tm * 4 + r;
        float* sp = skips + (size_t)row * 128 + c0;
        float4 s0 = *(float4*)sp;
        float4 s1 = *(float4*)(sp + 4);
        s0.x += acc2[r][0] + bs0.x; s0.y += acc2[r][1] + bs0.y;
        s0.z += acc2[r][2] + bs0.z; s0.w += acc2[r][3] + bs0.w;
        s1.x += acc2[r][4] + bs1.x; s1.y += acc2[r][5] + bs1.y;
        s1.z += acc2[r][6] + bs1.z; s1.w += acc2[r][7] + bs1.w;
        *(float4*)sp = s0; *(float4*)(sp + 4) = s1;
        const float* xp = x + (size_t)row * 128 + c0;
        const float4 x0 = *(const float4*)xp;
        const float4 x1 = *(const float4*)(xp + 4);
        float4 o0, o1;
        o0.x = (x0.x + acc2[r][8]  + bo0.x) * SQRT_HALF;
        o0.y = (x0.y + acc2[r][9]  + bo0.y) * SQRT_HALF;
        o0.z = (x0.z + acc2[r][10] + bo0.z) * SQRT_HALF;
        o0.w = (x0.w + acc2[r][11] + bo0.w) * SQRT_HALF;
        o1.x = (x1.x + acc2[r][12] + bo1.x) * SQRT_HALF;
        o1.y = (x1.y + acc2[r][13] + bo1.y) * SQRT_HALF;
        o1.z = (x1.z + acc2[r][14] + bo1.z) * SQRT_HALF;
        o1.w = (x1.w + acc2[r][15] + bo1.w) * SQRT_HALF;
        *(float4*)(xn + (size_t)row * 128 + c0)     = o0;
        *(float4*)(xn + (size_t)row * 128 + c0 + 4) = o1;
    }
}

// ------------------------------------------------------------- final stack ---
__launch_bounds__(256, 2)
__global__ void final_k(const float* __restrict__ skips,
                        const float* __restrict__ W1, const float* __restrict__ b1,
                        const float* __restrict__ W2, const float* __restrict__ b2,
                        float* __restrict__ out)
{
    __shared__ __align__(16) float A[16][68];
    __shared__ __align__(16) float Bm[16 * 256];
    __shared__ __align__(16) float zt[128][68];
    const int tid = threadIdx.x, tn = tid & 15, tm = tid >> 4;
    const int arow = tid >> 2, ak4 = (tid & 3) * 4, r0 = blockIdx.x * 64;
    const int c0 = tn * 8;
    float acc[4][8];
#pragma unroll
    for (int r = 0; r < 4; ++r)
#pragma unroll
        for (int j = 0; j < 8; ++j) acc[r][j] = 0.f;
    float4 av, bv0, bv1;
    auto load1 = [&](int ch) {
        av = *(const float4*)(skips + (size_t)(r0 + arow) * 128 + ch * 16 + ak4);
        av.x = fmaxf(av.x, 0.f); av.y = fmaxf(av.y, 0.f);
        av.z = fmaxf(av.z, 0.f); av.w = fmaxf(av.w, 0.f);
        bv0 = *(const float4*)(W1 + ch * 2048 + tid * 4);
        bv1 = *(const float4*)(W1 + ch * 2048 + 1024 + tid * 4);
    };
    load1(0);
    for (int ch = 0; ch < 8; ++ch) {
        __syncthreads();
        A[ak4 + 0][arow] = av.x; A[ak4 + 1][arow] = av.y;
        A[ak4 + 2][arow] = av.z; A[ak4 + 3][arow] = av.w;
        *(float4*)(Bm + tid * 4) = bv0;
        *(float4*)(Bm + 1024 + tid * 4) = bv1;
        __syncthreads();
        if (ch < 7) load1(ch + 1);
#pragma unroll
        for (int k = 0; k < 16; ++k) {
            const float4 a4 = *(const float4*)&A[k][tm * 4];
            const float4 b0 = *(const float4*)&Bm[k * 128 + tn * 8];
            const float4 b1v = *(const float4*)&Bm[k * 128 + tn * 8 + 4];
            const float aa[4]  = {a4.x, a4.y, a4.z, a4.w};
            const float bb8[8] = {b0.x, b0.y, b0.z, b0.w, b1v.x, b1v.y, b1v.z, b1v.w};
#pragma unroll
            for (int r = 0; r < 4; ++r)
#pragma unroll
                for (int j = 0; j < 8; ++j) acc[r][j] += aa[r] * bb8[j];
        }
    }
#pragma unroll
    for (int r = 0; r < 4; ++r)
#pragma unroll
        for (int j = 0; j < 8; ++j) {
            float h = acc[r][j] + b1[c0 + j];
            zt[c0 + j][tm * 4 + r] = fmaxf(h, 0.f);
        }
    float acc2[4][16];
#pragma unroll
    for (int r = 0; r < 4; ++r)
#pragma unroll
        for (int j = 0; j < 16; ++j) acc2[r][j] = 0.f;
    float4 bv[4];
    auto load2 = [&](int ch) {
#pragma unroll
        for (int j = 0; j < 4; ++j)
            bv[j] = *(const float4*)(W2 + ch * 4096 + j * 1024 + tid * 4);
    };
    load2(0);
    for (int ch = 0; ch < 8; ++ch) {
        __syncthreads();
#pragma unroll
        for (int j = 0; j < 4; ++j) *(float4*)(Bm + j * 1024 + tid * 4) = bv[j];
        __syncthreads();
        if (ch < 7) load2(ch + 1);
#pragma unroll
        for (int k = 0; k < 16; ++k) {
            const float4 a4 = *(const float4*)&zt[ch * 16 + k][tm * 4];
            const float4 b0 = *(const float4*)&Bm[k * 256 + tn * 8];
            const float4 b1v = *(const float4*)&Bm[k * 256 + tn * 8 + 4];
            const float4 b2v = *(const float4*)&Bm[k * 256 + tn * 8 + 128];
            const float4 b3v = *(const float4*)&Bm[k * 256 + tn * 8 + 132];
            const float aa[4]   = {a4.x, a4.y, a4.z, a4.w};
            const float bb16[16] = {b0.x, b0.y, b0.z, b0.w, b1v.x, b1v.y, b1v.z, b1v.w,
                                    b2v.x, b2v.y, b2v.z, b2v.w, b3v.x, b3v.y, b3v.z, b3v.w};
#pragma unroll
            for (int r = 0; r < 4; ++r)
#pragma unroll
                for (int j = 0; j < 16; ++j) acc2[r][j] += aa[r] * bb16[j];
        }
    }
    const float4 fb0 = *(const float4*)(b2 + c0);
    const float4 fb1 = *(const float4*)(b2 + c0 + 4);
    const float4 fb2 = *(const float4*)(b2 + 128 + c0);
    const float4 fb3 = *(const float4*)(b2 + 128 + c0 + 4);
#pragma unroll
    for (int r = 0; r < 4; ++r) {
        const int row = r0 + tm * 4 + r;
        float* op = out + (size_t)row * 256;
        float4 o0 = {acc2[r][0] + fb0.x, acc2[r][1] + fb0.y, acc2[r][2] + fb0.z, acc2[r][3] + fb0.w};
        float4 o1 = {acc2[r][4] + fb1.x, acc2[r][5] + fb1.y, acc2[r][6] + fb1.z, acc2[r][7] + fb1.w};
        float4 o2 = {acc2[r][8] + fb2.x, acc2[r][9] + fb2.y, acc2[r][10] + fb2.z, acc2[r][11] + fb2.w};
        float4 o3 = {acc2[r][12] + fb3.x, acc2[r][13] + fb3.y, acc2[r][14] + fb3.z, acc2[r][15] + fb3.w};
        *(float4*)(op + c0)           = o0;
        *(float4*)(op + c0 + 4)       = o1;
        *(float4*)(op + 128 + c0)     = o2;
        *(float4*)(op + 128 + c0 + 4) = o3;
    }
}

// ---------------------------------------------------------------- launcher ---
extern "C" void kernel_launch(void* const* d_in, const int* in_sizes, int n_in,
                              void* d_out, int out_size, void* d_ws, size_t ws_size,
                              hipStream_t stream)
{
    const float* inputs  = (const float*)d_in[0];
    const float* c       = (const float*)d_in[1];
    const float* up_w0   = (const float*)d_in[2];
    const float* up_w1   = (const float*)d_in[3];
    const float* up_w2   = (const float*)d_in[4];
    const float* first_w = (const float*)d_in[5];
    const float* first_b = (const float*)d_in[6];
    const float* Wd      = (const float*)d_in[7];
    const float* bd      = (const float*)d_in[8];
    const float* Wc      = (const float*)d_in[9];
    const float* Ws      = (const float*)d_in[10];
    const float* bs      = (const float*)d_in[11];
    const float* Wo      = (const float*)d_in[12];
    const float* bo_     = (const float*)d_in[13];
    const float* f1w     = (const float*)d_in[14];
    const float* f1b     = (const float*)d_in[15];
    const float* f2w     = (const float*)d_in[16];
    const float* f2b     = (const float*)d_in[17];

    const int P = BB * MELSC;   // 640

    // ws layout (fast path), bytes:
    //   skips f32            :         0 .. 67,108,864
    //   w1h/w1l bf16         :  67,108,864 + 2*4,915,200
    //   w2h/w2l bf16         :  76,939,264 + 2*1,310,720
    //   condh/condl bf16     :  79,560,704 + 2*25,165,824  -> total 129,892,352
    const size_t NEED = 129892352u;

    if (ws_size >= NEED) {
        char* w = (char*)d_ws;
        float*          skips = (float*)w;
        unsigned short* w1h   = (unsigned short*)(w + 67108864);
        unsigned short* w1l   = w1h + (size_t)NBLK * 256 * KTOT;
        unsigned short* w2h   = (unsigned short*)(w + 76939264);
        unsigned short* w2l   = w2h + (size_t)NBLK * 256 * 128;
        unsigned short* condh = (unsigned short*)(w + 79560704);
        unsigned short* condl = condh + (size_t)BB * TA * CPAD;
        float* tmp1 = skips;              // overlay: dead before first_k_bf zeroes skips
        float* tmp2 = skips + 163840;

        // x as bf16 hi/lo ping-pong filling d_out exactly
        unsigned short* xh0 = (unsigned short*)d_out;
        unsigned short* xl0 = xh0 + (size_t)MROWS * RCH;
        unsigned short* xh1 = xl0 + (size_t)MROWS * RCH;
        unsigned short* xl1 = xh1 + (size_t)MROWS * RCH;

        prep_w1<<<(NBLK * 256 * KTOT + 255) / 256, 256, 0, stream>>>(Wd, Wc, w1h, w1l);
        prep_w2<<<(NBLK * 256 * 128 + 255) / 256, 256, 0, stream>>>(Ws, Wo, w2h, w2l);

        upsample_k<<<(P * 256 + 255) / 256, 256, 0, stream>>>(c, tmp1, up_w0, 64, 256, 4, 8, 5, P, 0);
        upsample_k<<<(P * 2048 + 255) / 256, 256, 0, stream>>>(tmp1, tmp2, up_w1, 256, 2048, 8, 16, 11, P, 0);
        upsample_cond_k<<<(BB * CPAD * TA + 255) / 256, 256, 0, stream>>>(tmp2, condh, condl, up_w2, 2048, 8, 16, 11);

        first_k_bf<<<MROWS / 64, 256, 0, stream>>>(inputs, first_w, first_b, xh0, xl0, skips);

        const unsigned short* sh = xh0; const unsigned short* sl = xl0;
        unsigned short*       dh = xh1; unsigned short*       dl = xl1;
        for (int i = 0; i < NBLK; ++i) {
            const int d = 1 << (i % 10);
            block_k_mfma<<<MROWS / 64, 256, 0, stream>>>(
                sh, sl, dh, dl, condh, condl, skips,
                w1h + (size_t)i * 256 * KTOT, w1l + (size_t)i * 256 * KTOT,
                w2h + (size_t)i * 256 * 128, w2l + (size_t)i * 256 * 128,
                bd + i * 256, bs + i * 128, bo_ + i * 128, d);
            const unsigned short* th = sh; const unsigned short* tl = sl;
            sh = dh; sl = dl; dh = (unsigned short*)th; dl = (unsigned short*)tl;
        }
        final_k<<<MROWS / 64, 256, 0, stream>>>(skips, f1w, f1b, f2w, f2b, (float*)d_out);
    } else {
        // -------- fallback: proven fp32 path (round 4) --------
        float* ws    = (float*)d_ws;
        float* cond  = ws;
        float* skips = ws + (size_t)BB * TA * MELSC;
        float* tmp1  = skips;
        float* tmp2  = skips + 163840;
        float* xa = (float*)d_out;
        float* xb = xa + (size_t)MROWS * RCH;

        upsample_k<<<(P * 256 + 255) / 256, 256, 0, stream>>>(c, tmp1, up_w0, 64, 256, 4, 8, 5, P, 0);
        upsample_k<<<(P * 2048 + 255) / 256, 256, 0, stream>>>(tmp1, tmp2, up_w1, 256, 2048, 8, 16, 11, P, 0);
        upsample_k<<<(P * TA + 255) / 256, 256, 0, stream>>>(tmp2, cond, up_w2, 2048, TA, 8, 16, 11, P, 1);
        first_k<<<MROWS / 64, 256, 0, stream>>>(inputs, first_w, first_b, xa, skips);
        const float* xs = xa; float* xd = xb;
        for (int i = 0; i < NBLK; ++i) {
            const int d = 1 << (i % 10);
            block_k<<<MROWS / 64, 256, 0, stream>>>(
                xs, xd, cond, skips,
                Wd + (size_t)i * 3 * 128 * 256, bd + i * 256,
                Wc + (size_t)i * 80 * 256,
                Ws + (size_t)i * 128 * 128, bs + i * 128,
                Wo + (size_t)i * 128 * 128, bo_ + i * 128, d);
            float* t = (float*)xs; xs = xd; xd = t;
        }
        final_k<<<MROWS / 64, 256, 0, stream>>>(skips, f1w, f1b, f2w, f2b, (float*)d_out);
    }
}